// Round 8
// baseline (356.077 us; speedup 1.0000x reference)
//
#include <hip/hip_runtime.h>

#define NN 50000
#define NE 800000
#define NG 8
#define BN_EPS 1e-5f
#define NBLK ((NN + 255) / 256)
#define POOL_BLOCKS 512
#define NPART 8
#define HLD 192   // dedup'd H row width: [c0|c1|c2]

typedef __attribute__((ext_vector_type(8))) short bf16x8;
typedef __attribute__((ext_vector_type(4))) float f32x4;

static __device__ __forceinline__ unsigned short f2bf(float f) {
    unsigned int u = __float_as_uint(f);
    unsigned int r = (u + 0x7FFFu + ((u >> 16) & 1u)) >> 16;   // RNE
    return (unsigned short)r;
}
static __device__ __forceinline__ float bf2f(unsigned short h) {
    return __uint_as_float((unsigned int)h << 16);
}

// ---------------- CSR build ----------------

__global__ __launch_bounds__(256) void count_deg(const int* __restrict__ dst,
                                                 int* __restrict__ degi) {
    int e = blockIdx.x * 256 + threadIdx.x;
    if (e < NE) atomicAdd(&degi[dst[e]], 1);
}

__global__ __launch_bounds__(256) void compute_dinv_xs(const int* __restrict__ degi,
                                                       const float* __restrict__ x,
                                                       float* __restrict__ dinv,
                                                       float* __restrict__ xs) {
    int i = blockIdx.x * 256 + threadIdx.x;
    if (i < NN) {
        float di = rsqrtf((float)(degi[i] + 1));
        dinv[i] = di;
        xs[i * 3 + 0] = x[i * 3 + 0] * di;
        xs[i * 3 + 1] = x[i * 3 + 1] * di;
        xs[i * 3 + 2] = x[i * 3 + 2] * di;
    }
}

__global__ __launch_bounds__(256) void scan_partial(const int* __restrict__ degi,
                                                    int* __restrict__ rowptr,
                                                    int* __restrict__ bsum) {
    __shared__ int sh[256];
    const int tid = threadIdx.x;
    const int i = blockIdx.x * 256 + tid;
    int v = (i < NN) ? degi[i] : 0;
    sh[tid] = v;
    __syncthreads();
#pragma unroll
    for (int off = 1; off < 256; off <<= 1) {
        int t = (tid >= off) ? sh[tid - off] : 0;
        __syncthreads();
        sh[tid] += t;
        __syncthreads();
    }
    if (i < NN) rowptr[i] = sh[tid] - v;
    if (tid == 255) bsum[blockIdx.x] = sh[255];
}

__global__ __launch_bounds__(256) void scan_bsums(int* __restrict__ bsum) {
    __shared__ int sh[256];
    const int tid = threadIdx.x;
    int v = (tid < NBLK) ? bsum[tid] : 0;
    sh[tid] = v;
    __syncthreads();
#pragma unroll
    for (int off = 1; off < 256; off <<= 1) {
        int t = (tid >= off) ? sh[tid - off] : 0;
        __syncthreads();
        sh[tid] += t;
        __syncthreads();
    }
    if (tid < NBLK) bsum[tid] = sh[tid] - v;
}

__global__ __launch_bounds__(256) void scan_finalize(const int* __restrict__ bsum,
                                                     int* __restrict__ rowptr,
                                                     int* __restrict__ cursor) {
    const int i = blockIdx.x * 256 + threadIdx.x;
    if (i < NN) {
        int r = rowptr[i] + bsum[blockIdx.x];
        rowptr[i] = r;
        cursor[i] = r;
    }
    if (i == 0) rowptr[NN] = NE;
}

__global__ __launch_bounds__(256) void fill_csr(const int* __restrict__ src,
                                                const int* __restrict__ dst,
                                                int* __restrict__ cursor,
                                                unsigned short* __restrict__ esrc16) {
    int e = blockIdx.x * 256 + threadIdx.x;
    if (e < NE) {
        int s = src[e], d = dst[e];
        int p = atomicAdd(&cursor[d], 1);
        esrc16[p] = (unsigned short)s;
    }
}

// ---------------- W packs: fp32 [K,NOUT] -> hi/lo bf16 in B-fragment order ----------------

__global__ __launch_bounds__(256) void pack_w(const float* __restrict__ W, int K, int NOUT,
                                              unsigned short* __restrict__ ph,
                                              unsigned short* __restrict__ pl) {
    int idx = blockIdx.x * 256 + threadIdx.x;
    if (idx >= K * NOUT) return;
    int j = idx & 7;
    int lane = (idx >> 3) & 63;
    int rest = idx >> 9;
    int NF = NOUT >> 4;
    int f = rest % NF, ks = rest / NF;
    int k = ks * 32 + (lane >> 4) * 8 + j;
    int col = f * 16 + (lane & 15);
    float v = W[k * NOUT + col];
    unsigned short hi = f2bf(v);
    ph[idx] = hi;
    pl[idx] = f2bf(v - bf2f(hi));
}

// enc_w0 [256,128] -> pre-summed K=192 pack: rows {k,k+64} summed for k<64, else row k+64
__global__ __launch_bounds__(256) void pack_we0(const float* __restrict__ W,
                                                unsigned short* __restrict__ ph,
                                                unsigned short* __restrict__ pl) {
    const int K = 192, NOUT = 128;
    int idx = blockIdx.x * 256 + threadIdx.x;
    if (idx >= K * NOUT) return;
    int j = idx & 7;
    int lane = (idx >> 3) & 63;
    int rest = idx >> 9;
    int NF = NOUT >> 4;
    int f = rest % NF, ks = rest / NF;
    int k = ks * 32 + (lane >> 4) * 8 + j;
    int col = f * 16 + (lane & 15);
    float v = (k < 64) ? (W[k * NOUT + col] + W[(k + 64) * NOUT + col])
                       : W[(k + 64) * NOUT + col];
    unsigned short hi = f2bf(v);
    ph[idx] = hi;
    pl[idx] = f2bf(v - bf2f(hi));
}

// ---------------- split-bf16 MFMA GEMM ----------------
// MODE 0: out = (A@W)*dinv[row] -> quarter-major [NF][NN][16] fp32 (aggregation input)
// MODE 1: bias+relu -> hi/lo bf16 (row-major, ldo). MODE 2: bias+relu -> fp32 (row-major, ldo).

template<int K, int NF, int MODE>
__global__ __launch_bounds__(256) void mfma_gemm(
        const unsigned short* __restrict__ Ahi,
        const unsigned short* __restrict__ Alo, int lda,
        const unsigned short* __restrict__ Bph,
        const unsigned short* __restrict__ Bpl,
        const float* __restrict__ bias,
        const float* __restrict__ dinv,
        float* __restrict__ outF,
        unsigned short* __restrict__ outHi,
        unsigned short* __restrict__ outLo, int ldo) {
    const int wave = threadIdx.x >> 6;
    const int lane = threadIdx.x & 63;
    const int rbase = blockIdx.x * 64 + wave * 16;
    int arow = rbase + (lane & 15);
    if (arow >= NN) arow = NN - 1;
    const int kbase = (lane >> 4) * 8;

    f32x4 acc[NF];
#pragma unroll
    for (int f = 0; f < NF; f++) acc[f] = (f32x4){0.f, 0.f, 0.f, 0.f};

    const unsigned short* pa_hi = Ahi + (size_t)arow * lda + kbase;
    const unsigned short* pa_lo = Alo + (size_t)arow * lda + kbase;
    const unsigned short* pb_hi = Bph + lane * 8;
    const unsigned short* pb_lo = Bpl + lane * 8;

#pragma unroll
    for (int ks = 0; ks < K / 32; ks++) {
        bf16x8 ah = *reinterpret_cast<const bf16x8*>(pa_hi + ks * 32);
        bf16x8 al = *reinterpret_cast<const bf16x8*>(pa_lo + ks * 32);
#pragma unroll
        for (int f = 0; f < NF; f++) {
            bf16x8 bh = *reinterpret_cast<const bf16x8*>(pb_hi + (size_t)((ks * NF + f) * 64) * 8);
            bf16x8 bl = *reinterpret_cast<const bf16x8*>(pb_lo + (size_t)((ks * NF + f) * 64) * 8);
            acc[f] = __builtin_amdgcn_mfma_f32_16x16x32_bf16(ah, bh, acc[f], 0, 0, 0);
            acc[f] = __builtin_amdgcn_mfma_f32_16x16x32_bf16(ah, bl, acc[f], 0, 0, 0);
            acc[f] = __builtin_amdgcn_mfma_f32_16x16x32_bf16(al, bh, acc[f], 0, 0, 0);
        }
    }

    const int drow0 = rbase + (lane >> 4) * 4;
    const int dcol = lane & 15;
#pragma unroll
    for (int f = 0; f < NF; f++) {
#pragma unroll
        for (int r = 0; r < 4; r++) {
            int row = drow0 + r;
            if (row < NN) {
                float v = acc[f][r];
                if (MODE == 0) {
                    // quarter-major for L2-resident gather passes
                    outF[((size_t)f * NN + row) * 16 + dcol] = v * dinv[row];
                } else {
                    int col = f * 16 + dcol;
                    v = fmaxf(v + bias[col], 0.0f);
                    if (MODE == 1) {
                        unsigned short hi = f2bf(v);
                        outHi[(size_t)row * ldo + col] = hi;
                        outLo[(size_t)row * ldo + col] = f2bf(v - bf2f(hi));
                    } else {
                        outF[(size_t)row * ldo + col] = v;
                    }
                }
            }
        }
    }
}

// ---------------- layer 0: aggregate xs (3-wide, pre-scaled) per node ----------------

__global__ __launch_bounds__(256) void agg_x3(
        const float* __restrict__ xs,
        const int* __restrict__ rowptr,
        const unsigned short* __restrict__ esrc16,
        const float* __restrict__ dinv,
        float* __restrict__ ax) {
    const int i = blockIdx.x * 256 + threadIdx.x;
    if (i >= NN) return;
    float a0 = xs[i * 3 + 0];
    float a1 = xs[i * 3 + 1];
    float a2 = xs[i * 3 + 2];
    const int beg = rowptr[i], end = rowptr[i + 1];
    int e = beg;
    for (; e + 3 < end; e += 4) {
        int s0 = esrc16[e], s1 = esrc16[e + 1], s2 = esrc16[e + 2], s3 = esrc16[e + 3];
        a0 += xs[s0 * 3 + 0] + xs[s1 * 3 + 0] + xs[s2 * 3 + 0] + xs[s3 * 3 + 0];
        a1 += xs[s0 * 3 + 1] + xs[s1 * 3 + 1] + xs[s2 * 3 + 1] + xs[s3 * 3 + 1];
        a2 += xs[s0 * 3 + 2] + xs[s1 * 3 + 2] + xs[s2 * 3 + 2] + xs[s3 * 3 + 2];
    }
    for (; e < end; e++) {
        int s = esrc16[e];
        a0 += xs[s * 3 + 0];
        a1 += xs[s * 3 + 1];
        a2 += xs[s * 3 + 2];
    }
    const float di = dinv[i];
    ax[i * 3 + 0] = a0 * di;
    ax[i * 3 + 1] = a1 * di;
    ax[i * 3 + 2] = a2 * di;
}

// ---------------- layer 0 dense: c0 = relu(BN(ax @ W0 + b0)) -> H cols 0:64 ----------------

__global__ __launch_bounds__(256) void l0_bn_relu(
        const float* __restrict__ ax, const float* __restrict__ W0,
        const float* __restrict__ b, const float* __restrict__ g,
        const float* __restrict__ beta, const float* __restrict__ rm,
        const float* __restrict__ rv,
        unsigned short* __restrict__ Hhi, unsigned short* __restrict__ Hlo) {
    const int t = blockIdx.x * 256 + threadIdx.x;
    const int row = t >> 6;
    const int ch = t & 63;
    if (row >= NN) return;
    float a0 = ax[row * 3 + 0], a1 = ax[row * 3 + 1], a2 = ax[row * 3 + 2];
    float v = a0 * W0[0 * 64 + ch] + a1 * W0[1 * 64 + ch] + a2 * W0[2 * 64 + ch] + b[ch];
    float sc = g[ch] * rsqrtf(rv[ch] + BN_EPS);
    v = (v - rm[ch]) * sc + beta[ch];
    v = fmaxf(v, 0.0f);
    unsigned short hi = f2bf(v);
    Hhi[(size_t)row * HLD + ch] = hi;
    Hlo[(size_t)row * HLD + ch] = f2bf(v - bf2f(hi));
}

// ---------------- channel-quartered gather + BN + ReLU -> hi/lo H slice ----------------
// hws4: [4][NN][16] pre-scaled rows. Pass q gathers only its 3.2MB quarter (L2-resident).
// Wave = 16 channels x 4 edge-groups; cross-group reduce via shfl_xor.

__global__ __launch_bounds__(256) void gather_bn_relu_q(
        const float* __restrict__ hws4,
        const int* __restrict__ rowptr,
        const unsigned short* __restrict__ esrc16,
        const float* __restrict__ dinv,
        const float* __restrict__ b, const float* __restrict__ g,
        const float* __restrict__ beta, const float* __restrict__ rm,
        const float* __restrict__ rv,
        unsigned short* __restrict__ Hhi, unsigned short* __restrict__ Hlo, int cbase) {
    const int BPQ = NN / 4;                    // 12500 blocks per quarter
    const int q = blockIdx.x / BPQ;
    const int bin = blockIdx.x - q * BPQ;
    const int wave = threadIdx.x >> 6;
    const int lane = threadIdx.x & 63;
    const int wid = bin * 4 + wave;            // node id
    const int ch = lane & 15;
    const int grp = lane >> 4;
    const float* __restrict__ tab = hws4 + (size_t)q * NN * 16;
    const int beg = rowptr[wid], end = rowptr[wid + 1];
    float acc = 0.0f;
    int e = beg + grp;
    for (; e + 4 < end; e += 8) {
        int s0 = esrc16[e];
        int s1 = esrc16[e + 4];
        acc += tab[s0 * 16 + ch] + tab[s1 * 16 + ch];
    }
    if (e < end) acc += tab[esrc16[e] * 16 + ch];
    acc += __shfl_xor(acc, 16, 64);
    acc += __shfl_xor(acc, 32, 64);
    acc += tab[wid * 16 + ch];                 // self-loop (pre-scaled)
    acc *= dinv[wid];
    const int co = q * 16 + ch;                // output channel within this layer's 64
    float sc = g[co] * rsqrtf(rv[co] + BN_EPS);
    float v = (acc + b[co] - rm[co]) * sc + beta[co];
    v = fmaxf(v, 0.0f);
    if (grp == 0) {
        unsigned short hi = f2bf(v);
        Hhi[(size_t)wid * HLD + cbase + co] = hi;
        Hlo[(size_t)wid * HLD + cbase + co] = f2bf(v - bf2f(hi));
    }
}

// ---------------- per-graph mean pooling ----------------

__global__ __launch_bounds__(256) void pool_kernel(
        const float* __restrict__ e, const int* __restrict__ batch,
        float* __restrict__ gfeat_part, float* __restrict__ counts_part) {
    __shared__ float sh[4][NG][64];
    __shared__ float shc[4][NG];
    const int tid = threadIdx.x;
    const int ch = tid & 63;
    const int rg = tid >> 6;
    float acc[NG];
    float cnt[NG];
#pragma unroll
    for (int g = 0; g < NG; g++) { acc[g] = 0.0f; cnt[g] = 0.0f; }
    for (int i = blockIdx.x * 4 + rg; i < NN; i += POOL_BLOCKS * 4) {
        int b = batch[i];
        float v = e[i * 64 + ch];
#pragma unroll
        for (int g = 0; g < NG; g++) {
            acc[g] += (b == g) ? v : 0.0f;
            cnt[g] += (b == g) ? 1.0f : 0.0f;
        }
    }
#pragma unroll
    for (int g = 0; g < NG; g++) sh[rg][g][ch] = acc[g];
    if (ch == 0) {
#pragma unroll
        for (int g = 0; g < NG; g++) shc[rg][g] = cnt[g];
    }
    __syncthreads();
    const int p = blockIdx.x & (NPART - 1);
    if (rg == 0) {
#pragma unroll
        for (int g = 0; g < NG; g++) {
            float s = sh[0][g][ch] + sh[1][g][ch] + sh[2][g][ch] + sh[3][g][ch];
            atomicAdd(&gfeat_part[(p * NG + g) * 64 + ch], s);
        }
    }
    if (tid < NG) {
        float s = shc[0][tid] + shc[1][tid] + shc[2][tid] + shc[3][tid];
        atomicAdd(&counts_part[p * NG + tid], s);
    }
}

// ---------------- decoder ----------------

__global__ __launch_bounds__(256) void dec_kernel(
        const float* __restrict__ gfeat_part, const float* __restrict__ counts_part,
        const float* __restrict__ w0, const float* __restrict__ b0,
        const float* __restrict__ w1, const float* __restrict__ b1,
        float* __restrict__ out) {
    __shared__ float mg[NG][64];
    __shared__ float mc[NG];
    __shared__ float t1[NG][32];
    const int tid = threadIdx.x;
    for (int idx = tid; idx < NG * 64; idx += 256) {
        float s = 0.0f;
#pragma unroll
        for (int p = 0; p < NPART; p++) s += gfeat_part[p * NG * 64 + idx];
        mg[idx >> 6][idx & 63] = s;
    }
    if (tid < NG) {
        float s = 0.0f;
#pragma unroll
        for (int p = 0; p < NPART; p++) s += counts_part[p * NG + tid];
        mc[tid] = s;
    }
    __syncthreads();
    const int g = tid >> 5, c = tid & 31;
    float inv = 1.0f / fmaxf(mc[g], 1.0f);
    float acc = b0[c];
    for (int k = 0; k < 64; k++)
        acc = fmaf(mg[g][k] * inv, w0[k * 32 + c], acc);
    t1[g][c] = fmaxf(acc, 0.0f);
    __syncthreads();
    if (tid < NG) {
        float o = b1[0];
        for (int c2 = 0; c2 < 32; c2++) o = fmaf(t1[tid][c2], w1[c2], o);
        out[tid] = o;
    }
}

// ---------------- launch ----------------

extern "C" void kernel_launch(void* const* d_in, const int* in_sizes, int n_in,
                              void* d_out, int out_size, void* d_ws, size_t ws_size,
                              hipStream_t stream) {
    const float* x      = (const float*)d_in[0];
    const int*   ei     = (const int*)d_in[1];
    const int*   batch  = (const int*)d_in[2];
    const float* W0     = (const float*)d_in[3];
    const float* b0     = (const float*)d_in[4];
    const float* g0     = (const float*)d_in[5];
    const float* beta0  = (const float*)d_in[6];
    const float* rm0    = (const float*)d_in[7];
    const float* rv0    = (const float*)d_in[8];
    const float* W1     = (const float*)d_in[9];
    const float* b1     = (const float*)d_in[10];
    const float* g1     = (const float*)d_in[11];
    const float* beta1  = (const float*)d_in[12];
    const float* rm1    = (const float*)d_in[13];
    const float* rv1    = (const float*)d_in[14];
    const float* W2     = (const float*)d_in[15];
    const float* b2     = (const float*)d_in[16];
    const float* g2     = (const float*)d_in[17];
    const float* beta2  = (const float*)d_in[18];
    const float* rm2    = (const float*)d_in[19];
    const float* rv2    = (const float*)d_in[20];
    const float* enc_w0 = (const float*)d_in[21];
    const float* enc_b0 = (const float*)d_in[22];
    const float* enc_w1 = (const float*)d_in[23];
    const float* enc_b1 = (const float*)d_in[24];
    const float* dec_w0 = (const float*)d_in[25];
    const float* dec_b0 = (const float*)d_in[26];
    const float* dec_w1 = (const float*)d_in[27];
    const float* dec_b1 = (const float*)d_in[28];

    const int* esrc = ei;
    const int* edst = ei + NE;

    char* wsb = (char*)d_ws;
    unsigned short* Hhi = (unsigned short*)wsb;                       // [NN*192]
    unsigned short* Hlo = Hhi + (size_t)NN * HLD;                     // [NN*192]
    char* U = (char*)(Hlo + (size_t)NN * HLD);                        // union region
    unsigned short* Thi = (unsigned short*)U;                         // [NN*128]
    unsigned short* Tlo = Thi + (size_t)NN * 128;                     // [NN*128]
    int*   degi   = (int*)U;                                          // [NN]
    int*   rowptr = degi + NN;                                        // [NN+1]
    int*   cursor = rowptr + NN + 1;                                  // [NN]
    unsigned short* esrc16 = (unsigned short*)(cursor + NN);          // [NE] u16
    float* hws    = (float*)(U + (size_t)NN * 128 * 2 * sizeof(unsigned short)); // [4][NN][16] / [NN,64]
    float* dinv   = hws + (size_t)NN * 64;
    float* xs     = dinv + NN;                                        // [NN*3]
    float* ax     = xs + (size_t)NN * 3;                              // [NN*3]
    float* gfeat_part  = ax + (size_t)NN * 3;
    float* counts_part = gfeat_part + NPART * NG * 64;
    int*   bsum   = (int*)(counts_part + NPART * NG);
    unsigned short* wp = (unsigned short*)(bsum + NBLK);
    unsigned short* Wp1h = wp;              unsigned short* Wp1l = Wp1h + 64 * 64;
    unsigned short* Wp2h = Wp1l + 64 * 64;  unsigned short* Wp2l = Wp2h + 128 * 64;
    unsigned short* We0h = Wp2l + 128 * 64; unsigned short* We0l = We0h + 192 * 128;
    unsigned short* We1h = We0l + 192 * 128;unsigned short* We1l = We1h + 128 * 64;

    hipMemsetAsync(gfeat_part, 0, (NPART * NG * 64 + NPART * NG) * sizeof(float), stream);
    hipMemsetAsync(degi, 0, NN * sizeof(int), stream);

    // CSR build
    count_deg<<<(NE + 255) / 256, 256, 0, stream>>>(edst, degi);
    compute_dinv_xs<<<NBLK, 256, 0, stream>>>(degi, x, dinv, xs);
    scan_partial<<<NBLK, 256, 0, stream>>>(degi, rowptr, bsum);
    scan_bsums<<<1, 256, 0, stream>>>(bsum);
    scan_finalize<<<NBLK, 256, 0, stream>>>(bsum, rowptr, cursor);
    fill_csr<<<(NE + 255) / 256, 256, 0, stream>>>(esrc, edst, cursor, esrc16);

    // W packs
    pack_w<<<(64 * 64 + 255) / 256, 256, 0, stream>>>(W1, 64, 64, Wp1h, Wp1l);
    pack_w<<<(128 * 64 + 255) / 256, 256, 0, stream>>>(W2, 128, 64, Wp2h, Wp2l);
    pack_we0<<<(192 * 128 + 255) / 256, 256, 0, stream>>>(enc_w0, We0h, We0l);
    pack_w<<<(128 * 64 + 255) / 256, 256, 0, stream>>>(enc_w1, 128, 64, We1h, We1l);

    const int GRID_MFMA = (NN + 63) / 64;
    const int GRID_L0   = (NN * 64 + 255) / 256;
    const int GRID_GQ   = NN;              // 4 quarters x (NN/4) blocks, 4 nodes/block

    // ---- layer 0: aggregate pre-scaled xs, then fused dense+BN+relu -> H[:,0:64] ----
    agg_x3<<<NBLK, 256, 0, stream>>>(xs, rowptr, esrc16, dinv, ax);
    l0_bn_relu<<<GRID_L0, 256, 0, stream>>>(ax, W0, b0, g0, beta0, rm0, rv0, Hhi, Hlo);

    // ---- layer 1: hws4 = dinv*(H[:,0:64] @ W1) ; quartered gather -> H[:,64:128] ----
    mfma_gemm<64, 4, 0><<<GRID_MFMA, 256, 0, stream>>>(Hhi, Hlo, HLD, Wp1h, Wp1l,
                                                       nullptr, dinv, hws, nullptr, nullptr, 0);
    gather_bn_relu_q<<<GRID_GQ, 256, 0, stream>>>(hws, rowptr, esrc16, dinv,
                                                  b1, g1, beta1, rm1, rv1, Hhi, Hlo, 64);

    // ---- layer 2: hws4 = dinv*(H[:,0:128] @ W2) ; quartered gather -> H[:,128:192] ----
    mfma_gemm<128, 4, 0><<<GRID_MFMA, 256, 0, stream>>>(Hhi, Hlo, HLD, Wp2h, Wp2l,
                                                        nullptr, dinv, hws, nullptr, nullptr, 0);
    gather_bn_relu_q<<<GRID_GQ, 256, 0, stream>>>(hws, rowptr, esrc16, dinv,
                                                  b2, g2, beta2, rm2, rv2, Hhi, Hlo, 128);

    // ---- encoder (K=192 with pre-summed c0 weights; T overwrites CSR region) ----
    mfma_gemm<192, 8, 1><<<GRID_MFMA, 256, 0, stream>>>(Hhi, Hlo, HLD, We0h, We0l,
                                                        enc_b0, nullptr, nullptr, Thi, Tlo, 128);
    mfma_gemm<128, 4, 2><<<GRID_MFMA, 256, 0, stream>>>(Thi, Tlo, 128, We1h, We1l,
                                                        enc_b1, nullptr, hws, nullptr, nullptr, 64);

    // ---- pool + decode ----
    pool_kernel<<<POOL_BLOCKS, 256, 0, stream>>>(hws, batch, gfeat_part, counts_part);
    dec_kernel<<<1, 256, 0, stream>>>(gfeat_part, counts_part, dec_w0, dec_b0, dec_w1, dec_b1, (float*)d_out);
}

// Round 9
// 260.467 us; speedup vs baseline: 1.3671x; 1.3671x over previous
//
#include <hip/hip_runtime.h>
#include <hip/hip_fp16.h>

#define NN 50000
#define NE 800000
#define NG 8
#define BN_EPS 1e-5f
#define NBLK ((NN + 255) / 256)
#define POOL_BLOCKS 512
#define NPART 8
#define HLD 192   // dedup'd H row width: [c0|c1|c2]

typedef __attribute__((ext_vector_type(8))) short bf16x8;
typedef __attribute__((ext_vector_type(4))) float f32x4;

static __device__ __forceinline__ unsigned short f2bf(float f) {
    unsigned int u = __float_as_uint(f);
    unsigned int r = (u + 0x7FFFu + ((u >> 16) & 1u)) >> 16;   // RNE
    return (unsigned short)r;
}
static __device__ __forceinline__ float bf2f(unsigned short h) {
    return __uint_as_float((unsigned int)h << 16);
}

// ---------------- CSR build ----------------

__global__ __launch_bounds__(256) void count_deg(const int* __restrict__ dst,
                                                 int* __restrict__ degi) {
    int e = blockIdx.x * 256 + threadIdx.x;
    if (e < NE) atomicAdd(&degi[dst[e]], 1);
}

__global__ __launch_bounds__(256) void compute_dinv_xs(const int* __restrict__ degi,
                                                       const float* __restrict__ x,
                                                       float* __restrict__ dinv,
                                                       float* __restrict__ xs) {
    int i = blockIdx.x * 256 + threadIdx.x;
    if (i < NN) {
        float di = rsqrtf((float)(degi[i] + 1));
        dinv[i] = di;
        xs[i * 3 + 0] = x[i * 3 + 0] * di;
        xs[i * 3 + 1] = x[i * 3 + 1] * di;
        xs[i * 3 + 2] = x[i * 3 + 2] * di;
    }
}

__global__ __launch_bounds__(256) void scan_partial(const int* __restrict__ degi,
                                                    int* __restrict__ rowptr,
                                                    int* __restrict__ bsum) {
    __shared__ int sh[256];
    const int tid = threadIdx.x;
    const int i = blockIdx.x * 256 + tid;
    int v = (i < NN) ? degi[i] : 0;
    sh[tid] = v;
    __syncthreads();
#pragma unroll
    for (int off = 1; off < 256; off <<= 1) {
        int t = (tid >= off) ? sh[tid - off] : 0;
        __syncthreads();
        sh[tid] += t;
        __syncthreads();
    }
    if (i < NN) rowptr[i] = sh[tid] - v;
    if (tid == 255) bsum[blockIdx.x] = sh[255];
}

__global__ __launch_bounds__(256) void scan_bsums(int* __restrict__ bsum) {
    __shared__ int sh[256];
    const int tid = threadIdx.x;
    int v = (tid < NBLK) ? bsum[tid] : 0;
    sh[tid] = v;
    __syncthreads();
#pragma unroll
    for (int off = 1; off < 256; off <<= 1) {
        int t = (tid >= off) ? sh[tid - off] : 0;
        __syncthreads();
        sh[tid] += t;
        __syncthreads();
    }
    if (tid < NBLK) bsum[tid] = sh[tid] - v;
}

__global__ __launch_bounds__(256) void scan_finalize(const int* __restrict__ bsum,
                                                     int* __restrict__ rowptr,
                                                     int* __restrict__ cursor) {
    const int i = blockIdx.x * 256 + threadIdx.x;
    if (i < NN) {
        int r = rowptr[i] + bsum[blockIdx.x];
        rowptr[i] = r;
        cursor[i] = r;
    }
    if (i == 0) rowptr[NN] = NE;
}

__global__ __launch_bounds__(256) void fill_csr(const int* __restrict__ src,
                                                const int* __restrict__ dst,
                                                int* __restrict__ cursor,
                                                unsigned short* __restrict__ esrc16) {
    int e = blockIdx.x * 256 + threadIdx.x;
    if (e < NE) {
        int s = src[e], d = dst[e];
        int p = atomicAdd(&cursor[d], 1);
        esrc16[p] = (unsigned short)s;
    }
}

// ---------------- W packs: fp32 [K,NOUT] -> hi/lo bf16 in B-fragment order ----------------

__global__ __launch_bounds__(256) void pack_w(const float* __restrict__ W, int K, int NOUT,
                                              unsigned short* __restrict__ ph,
                                              unsigned short* __restrict__ pl) {
    int idx = blockIdx.x * 256 + threadIdx.x;
    if (idx >= K * NOUT) return;
    int j = idx & 7;
    int lane = (idx >> 3) & 63;
    int rest = idx >> 9;
    int NF = NOUT >> 4;
    int f = rest % NF, ks = rest / NF;
    int k = ks * 32 + (lane >> 4) * 8 + j;
    int col = f * 16 + (lane & 15);
    float v = W[k * NOUT + col];
    unsigned short hi = f2bf(v);
    ph[idx] = hi;
    pl[idx] = f2bf(v - bf2f(hi));
}

// enc_w0 [256,128] -> pre-summed K=192 pack (c0 appears twice in original concat)
__global__ __launch_bounds__(256) void pack_we0(const float* __restrict__ W,
                                                unsigned short* __restrict__ ph,
                                                unsigned short* __restrict__ pl) {
    const int K = 192, NOUT = 128;
    int idx = blockIdx.x * 256 + threadIdx.x;
    if (idx >= K * NOUT) return;
    int j = idx & 7;
    int lane = (idx >> 3) & 63;
    int rest = idx >> 9;
    int NF = NOUT >> 4;
    int f = rest % NF, ks = rest / NF;
    int k = ks * 32 + (lane >> 4) * 8 + j;
    int col = f * 16 + (lane & 15);
    float v = (k < 64) ? (W[k * NOUT + col] + W[(k + 64) * NOUT + col])
                       : W[(k + 64) * NOUT + col];
    unsigned short hi = f2bf(v);
    ph[idx] = hi;
    pl[idx] = f2bf(v - bf2f(hi));
}

// ---------------- split-bf16 MFMA GEMM ----------------
// MODE 0: out = fp16( (A@W) * dinv[row] ) row-major [NN,64] (gather table)
// MODE 1: bias+relu -> hi/lo bf16 (row-major, ldo). MODE 2: bias+relu -> fp32 (row-major, ldo).

template<int K, int NF, int MODE>
__global__ __launch_bounds__(256) void mfma_gemm(
        const unsigned short* __restrict__ Ahi,
        const unsigned short* __restrict__ Alo, int lda,
        const unsigned short* __restrict__ Bph,
        const unsigned short* __restrict__ Bpl,
        const float* __restrict__ bias,
        const float* __restrict__ dinv,
        float* __restrict__ outF,
        __half* __restrict__ outH,
        unsigned short* __restrict__ outHi,
        unsigned short* __restrict__ outLo, int ldo) {
    const int wave = threadIdx.x >> 6;
    const int lane = threadIdx.x & 63;
    const int rbase = blockIdx.x * 64 + wave * 16;
    int arow = rbase + (lane & 15);
    if (arow >= NN) arow = NN - 1;
    const int kbase = (lane >> 4) * 8;

    f32x4 acc[NF];
#pragma unroll
    for (int f = 0; f < NF; f++) acc[f] = (f32x4){0.f, 0.f, 0.f, 0.f};

    const unsigned short* pa_hi = Ahi + (size_t)arow * lda + kbase;
    const unsigned short* pa_lo = Alo + (size_t)arow * lda + kbase;
    const unsigned short* pb_hi = Bph + lane * 8;
    const unsigned short* pb_lo = Bpl + lane * 8;

#pragma unroll
    for (int ks = 0; ks < K / 32; ks++) {
        bf16x8 ah = *reinterpret_cast<const bf16x8*>(pa_hi + ks * 32);
        bf16x8 al = *reinterpret_cast<const bf16x8*>(pa_lo + ks * 32);
#pragma unroll
        for (int f = 0; f < NF; f++) {
            bf16x8 bh = *reinterpret_cast<const bf16x8*>(pb_hi + (size_t)((ks * NF + f) * 64) * 8);
            bf16x8 bl = *reinterpret_cast<const bf16x8*>(pb_lo + (size_t)((ks * NF + f) * 64) * 8);
            acc[f] = __builtin_amdgcn_mfma_f32_16x16x32_bf16(ah, bh, acc[f], 0, 0, 0);
            acc[f] = __builtin_amdgcn_mfma_f32_16x16x32_bf16(ah, bl, acc[f], 0, 0, 0);
            acc[f] = __builtin_amdgcn_mfma_f32_16x16x32_bf16(al, bh, acc[f], 0, 0, 0);
        }
    }

    const int drow0 = rbase + (lane >> 4) * 4;
    const int dcol = lane & 15;
#pragma unroll
    for (int f = 0; f < NF; f++) {
#pragma unroll
        for (int r = 0; r < 4; r++) {
            int row = drow0 + r;
            if (row < NN) {
                int col = f * 16 + dcol;
                float v = acc[f][r];
                if (MODE == 0) {
                    outH[(size_t)row * 64 + col] = __float2half(v * dinv[row]);
                } else {
                    v = fmaxf(v + bias[col], 0.0f);
                    if (MODE == 1) {
                        unsigned short hi = f2bf(v);
                        outHi[(size_t)row * ldo + col] = hi;
                        outLo[(size_t)row * ldo + col] = f2bf(v - bf2f(hi));
                    } else {
                        outF[(size_t)row * ldo + col] = v;
                    }
                }
            }
        }
    }
}

// ---------------- layer 0: aggregate xs (3-wide, pre-scaled) per node ----------------

__global__ __launch_bounds__(256) void agg_x3(
        const float* __restrict__ xs,
        const int* __restrict__ rowptr,
        const unsigned short* __restrict__ esrc16,
        const float* __restrict__ dinv,
        float* __restrict__ ax) {
    const int i = blockIdx.x * 256 + threadIdx.x;
    if (i >= NN) return;
    float a0 = xs[i * 3 + 0];
    float a1 = xs[i * 3 + 1];
    float a2 = xs[i * 3 + 2];
    const int beg = rowptr[i], end = rowptr[i + 1];
    int e = beg;
    for (; e + 3 < end; e += 4) {
        int s0 = esrc16[e], s1 = esrc16[e + 1], s2 = esrc16[e + 2], s3 = esrc16[e + 3];
        a0 += xs[s0 * 3 + 0] + xs[s1 * 3 + 0] + xs[s2 * 3 + 0] + xs[s3 * 3 + 0];
        a1 += xs[s0 * 3 + 1] + xs[s1 * 3 + 1] + xs[s2 * 3 + 1] + xs[s3 * 3 + 1];
        a2 += xs[s0 * 3 + 2] + xs[s1 * 3 + 2] + xs[s2 * 3 + 2] + xs[s3 * 3 + 2];
    }
    for (; e < end; e++) {
        int s = esrc16[e];
        a0 += xs[s * 3 + 0];
        a1 += xs[s * 3 + 1];
        a2 += xs[s * 3 + 2];
    }
    const float di = dinv[i];
    ax[i * 3 + 0] = a0 * di;
    ax[i * 3 + 1] = a1 * di;
    ax[i * 3 + 2] = a2 * di;
}

// ---------------- layer 0 dense: c0 = relu(BN(ax @ W0 + b0)) -> H cols 0:64 ----------------

__global__ __launch_bounds__(256) void l0_bn_relu(
        const float* __restrict__ ax, const float* __restrict__ W0,
        const float* __restrict__ b, const float* __restrict__ g,
        const float* __restrict__ beta, const float* __restrict__ rm,
        const float* __restrict__ rv,
        unsigned short* __restrict__ Hhi, unsigned short* __restrict__ Hlo) {
    const int t = blockIdx.x * 256 + threadIdx.x;
    const int row = t >> 6;
    const int ch = t & 63;
    if (row >= NN) return;
    float a0 = ax[row * 3 + 0], a1 = ax[row * 3 + 1], a2 = ax[row * 3 + 2];
    float v = a0 * W0[0 * 64 + ch] + a1 * W0[1 * 64 + ch] + a2 * W0[2 * 64 + ch] + b[ch];
    float sc = g[ch] * rsqrtf(rv[ch] + BN_EPS);
    v = (v - rm[ch]) * sc + beta[ch];
    v = fmaxf(v, 0.0f);
    unsigned short hi = f2bf(v);
    Hhi[(size_t)row * HLD + ch] = hi;
    Hlo[(size_t)row * HLD + ch] = f2bf(v - bf2f(hi));
}

// ---------------- fp16-table gather + BN + ReLU -> hi/lo H slice ----------------
// tab2: [NN][32] __half2 (64 ch, 128B rows). Wave = 2 edge-groups x 32 lanes x 2ch.

__global__ __launch_bounds__(256) void gather_bn_relu(
        const __half2* __restrict__ tab2,
        const int* __restrict__ rowptr,
        const unsigned short* __restrict__ esrc16,
        const float* __restrict__ dinv,
        const float* __restrict__ b, const float* __restrict__ g,
        const float* __restrict__ beta, const float* __restrict__ rm,
        const float* __restrict__ rv,
        unsigned short* __restrict__ Hhi, unsigned short* __restrict__ Hlo, int cbase) {
    const int wid = (blockIdx.x * 256 + threadIdx.x) >> 6;
    const int lane = threadIdx.x & 63;
    const int c2 = lane & 31;       // half2 index: channels 2*c2, 2*c2+1
    const int grp = lane >> 5;      // 0/1
    if (wid >= NN) return;
    const int beg = rowptr[wid], end = rowptr[wid + 1];
    float a0 = 0.0f, a1 = 0.0f;
    int e = beg + grp;
    for (; e + 6 < end; e += 8) {
        int s0 = esrc16[e], s1 = esrc16[e + 2], s2 = esrc16[e + 4], s3 = esrc16[e + 6];
        float2 f0 = __half22float2(tab2[(size_t)s0 * 32 + c2]);
        float2 f1 = __half22float2(tab2[(size_t)s1 * 32 + c2]);
        float2 f2 = __half22float2(tab2[(size_t)s2 * 32 + c2]);
        float2 f3 = __half22float2(tab2[(size_t)s3 * 32 + c2]);
        a0 += (f0.x + f1.x) + (f2.x + f3.x);
        a1 += (f0.y + f1.y) + (f2.y + f3.y);
    }
    for (; e < end; e += 2) {
        float2 f = __half22float2(tab2[(size_t)esrc16[e] * 32 + c2]);
        a0 += f.x;
        a1 += f.y;
    }
    a0 += __shfl_xor(a0, 32, 64);
    a1 += __shfl_xor(a1, 32, 64);
    float2 fs = __half22float2(tab2[(size_t)wid * 32 + c2]);  // self-loop
    a0 += fs.x;
    a1 += fs.y;
    const float di = dinv[wid];
    a0 *= di;
    a1 *= di;
    const int ch0 = 2 * c2, ch1 = 2 * c2 + 1;
    float v0 = (a0 + b[ch0] - rm[ch0]) * (g[ch0] * rsqrtf(rv[ch0] + BN_EPS)) + beta[ch0];
    float v1 = (a1 + b[ch1] - rm[ch1]) * (g[ch1] * rsqrtf(rv[ch1] + BN_EPS)) + beta[ch1];
    v0 = fmaxf(v0, 0.0f);
    v1 = fmaxf(v1, 0.0f);
    if (grp == 0) {
        unsigned short h0 = f2bf(v0), h1 = f2bf(v1);
        unsigned short l0 = f2bf(v0 - bf2f(h0)), l1 = f2bf(v1 - bf2f(h1));
        size_t o = (size_t)wid * HLD + cbase + ch0;   // even -> 4B aligned
        *reinterpret_cast<unsigned int*>(&Hhi[o]) = (unsigned int)h0 | ((unsigned int)h1 << 16);
        *reinterpret_cast<unsigned int*>(&Hlo[o]) = (unsigned int)l0 | ((unsigned int)l1 << 16);
    }
}

// ---------------- per-graph mean pooling ----------------

__global__ __launch_bounds__(256) void pool_kernel(
        const float* __restrict__ e, const int* __restrict__ batch,
        float* __restrict__ gfeat_part, float* __restrict__ counts_part) {
    __shared__ float sh[4][NG][64];
    __shared__ float shc[4][NG];
    const int tid = threadIdx.x;
    const int ch = tid & 63;
    const int rg = tid >> 6;
    float acc[NG];
    float cnt[NG];
#pragma unroll
    for (int g = 0; g < NG; g++) { acc[g] = 0.0f; cnt[g] = 0.0f; }
    for (int i = blockIdx.x * 4 + rg; i < NN; i += POOL_BLOCKS * 4) {
        int b = batch[i];
        float v = e[i * 64 + ch];
#pragma unroll
        for (int g = 0; g < NG; g++) {
            acc[g] += (b == g) ? v : 0.0f;
            cnt[g] += (b == g) ? 1.0f : 0.0f;
        }
    }
#pragma unroll
    for (int g = 0; g < NG; g++) sh[rg][g][ch] = acc[g];
    if (ch == 0) {
#pragma unroll
        for (int g = 0; g < NG; g++) shc[rg][g] = cnt[g];
    }
    __syncthreads();
    const int p = blockIdx.x & (NPART - 1);
    if (rg == 0) {
#pragma unroll
        for (int g = 0; g < NG; g++) {
            float s = sh[0][g][ch] + sh[1][g][ch] + sh[2][g][ch] + sh[3][g][ch];
            atomicAdd(&gfeat_part[(p * NG + g) * 64 + ch], s);
        }
    }
    if (tid < NG) {
        float s = shc[0][tid] + shc[1][tid] + shc[2][tid] + shc[3][tid];
        atomicAdd(&counts_part[p * NG + tid], s);
    }
}

// ---------------- decoder ----------------

__global__ __launch_bounds__(256) void dec_kernel(
        const float* __restrict__ gfeat_part, const float* __restrict__ counts_part,
        const float* __restrict__ w0, const float* __restrict__ b0,
        const float* __restrict__ w1, const float* __restrict__ b1,
        float* __restrict__ out) {
    __shared__ float mg[NG][64];
    __shared__ float mc[NG];
    __shared__ float t1[NG][32];
    const int tid = threadIdx.x;
    for (int idx = tid; idx < NG * 64; idx += 256) {
        float s = 0.0f;
#pragma unroll
        for (int p = 0; p < NPART; p++) s += gfeat_part[p * NG * 64 + idx];
        mg[idx >> 6][idx & 63] = s;
    }
    if (tid < NG) {
        float s = 0.0f;
#pragma unroll
        for (int p = 0; p < NPART; p++) s += counts_part[p * NG + tid];
        mc[tid] = s;
    }
    __syncthreads();
    const int g = tid >> 5, c = tid & 31;
    float inv = 1.0f / fmaxf(mc[g], 1.0f);
    float acc = b0[c];
    for (int k = 0; k < 64; k++)
        acc = fmaf(mg[g][k] * inv, w0[k * 32 + c], acc);
    t1[g][c] = fmaxf(acc, 0.0f);
    __syncthreads();
    if (tid < NG) {
        float o = b1[0];
        for (int c2 = 0; c2 < 32; c2++) o = fmaf(t1[tid][c2], w1[c2], o);
        out[tid] = o;
    }
}

// ---------------- launch ----------------

extern "C" void kernel_launch(void* const* d_in, const int* in_sizes, int n_in,
                              void* d_out, int out_size, void* d_ws, size_t ws_size,
                              hipStream_t stream) {
    const float* x      = (const float*)d_in[0];
    const int*   ei     = (const int*)d_in[1];
    const int*   batch  = (const int*)d_in[2];
    const float* W0     = (const float*)d_in[3];
    const float* b0     = (const float*)d_in[4];
    const float* g0     = (const float*)d_in[5];
    const float* beta0  = (const float*)d_in[6];
    const float* rm0    = (const float*)d_in[7];
    const float* rv0    = (const float*)d_in[8];
    const float* W1     = (const float*)d_in[9];
    const float* b1     = (const float*)d_in[10];
    const float* g1     = (const float*)d_in[11];
    const float* beta1  = (const float*)d_in[12];
    const float* rm1    = (const float*)d_in[13];
    const float* rv1    = (const float*)d_in[14];
    const float* W2     = (const float*)d_in[15];
    const float* b2     = (const float*)d_in[16];
    const float* g2     = (const float*)d_in[17];
    const float* beta2  = (const float*)d_in[18];
    const float* rm2    = (const float*)d_in[19];
    const float* rv2    = (const float*)d_in[20];
    const float* enc_w0 = (const float*)d_in[21];
    const float* enc_b0 = (const float*)d_in[22];
    const float* enc_w1 = (const float*)d_in[23];
    const float* enc_b1 = (const float*)d_in[24];
    const float* dec_w0 = (const float*)d_in[25];
    const float* dec_b0 = (const float*)d_in[26];
    const float* dec_w1 = (const float*)d_in[27];
    const float* dec_b1 = (const float*)d_in[28];

    const int* esrc = ei;
    const int* edst = ei + NE;

    char* wsb = (char*)d_ws;
    unsigned short* Hhi = (unsigned short*)wsb;                       // [NN*192]
    unsigned short* Hlo = Hhi + (size_t)NN * HLD;                     // [NN*192]
    char* U = (char*)(Hlo + (size_t)NN * HLD);                        // union region
    unsigned short* Thi = (unsigned short*)U;                         // [NN*128]
    unsigned short* Tlo = Thi + (size_t)NN * 128;                     // [NN*128]
    int*   degi   = (int*)U;                                          // [NN]
    int*   rowptr = degi + NN;                                        // [NN+1]
    int*   cursor = rowptr + NN + 1;                                  // [NN]
    unsigned short* esrc16 = (unsigned short*)(cursor + NN);          // [NE] u16
    float* hws    = (float*)(U + (size_t)NN * 128 * 2 * sizeof(unsigned short)); // [NN,64] fp32 (pool in)
    __half* tabh  = (__half*)hws;                                     // [NN,64] fp16 (gather table; dead before enc1)
    float* dinv   = hws + (size_t)NN * 64;
    float* xs     = dinv + NN;                                        // [NN*3]
    float* ax     = xs + (size_t)NN * 3;                              // [NN*3]
    float* gfeat_part  = ax + (size_t)NN * 3;
    float* counts_part = gfeat_part + NPART * NG * 64;
    int*   bsum   = (int*)(counts_part + NPART * NG);
    unsigned short* wp = (unsigned short*)(bsum + NBLK);
    unsigned short* Wp1h = wp;              unsigned short* Wp1l = Wp1h + 64 * 64;
    unsigned short* Wp2h = Wp1l + 64 * 64;  unsigned short* Wp2l = Wp2h + 128 * 64;
    unsigned short* We0h = Wp2l + 128 * 64; unsigned short* We0l = We0h + 192 * 128;
    unsigned short* We1h = We0l + 192 * 128;unsigned short* We1l = We1h + 128 * 64;

    hipMemsetAsync(gfeat_part, 0, (NPART * NG * 64 + NPART * NG) * sizeof(float), stream);
    hipMemsetAsync(degi, 0, NN * sizeof(int), stream);

    // CSR build
    count_deg<<<(NE + 255) / 256, 256, 0, stream>>>(edst, degi);
    compute_dinv_xs<<<NBLK, 256, 0, stream>>>(degi, x, dinv, xs);
    scan_partial<<<NBLK, 256, 0, stream>>>(degi, rowptr, bsum);
    scan_bsums<<<1, 256, 0, stream>>>(bsum);
    scan_finalize<<<NBLK, 256, 0, stream>>>(bsum, rowptr, cursor);
    fill_csr<<<(NE + 255) / 256, 256, 0, stream>>>(esrc, edst, cursor, esrc16);

    // W packs
    pack_w<<<(64 * 64 + 255) / 256, 256, 0, stream>>>(W1, 64, 64, Wp1h, Wp1l);
    pack_w<<<(128 * 64 + 255) / 256, 256, 0, stream>>>(W2, 128, 64, Wp2h, Wp2l);
    pack_we0<<<(192 * 128 + 255) / 256, 256, 0, stream>>>(enc_w0, We0h, We0l);
    pack_w<<<(128 * 64 + 255) / 256, 256, 0, stream>>>(enc_w1, 128, 64, We1h, We1l);

    const int GRID_MFMA = (NN + 63) / 64;
    const int GRID_64   = (NN * 64 + 255) / 256;

    // ---- layer 0: aggregate pre-scaled xs, then fused dense+BN+relu -> H[:,0:64] ----
    agg_x3<<<NBLK, 256, 0, stream>>>(xs, rowptr, esrc16, dinv, ax);
    l0_bn_relu<<<GRID_64, 256, 0, stream>>>(ax, W0, b0, g0, beta0, rm0, rv0, Hhi, Hlo);

    // ---- layer 1: tab = fp16(dinv*(H[:,0:64] @ W1)) ; gather -> H[:,64:128] ----
    mfma_gemm<64, 4, 0><<<GRID_MFMA, 256, 0, stream>>>(Hhi, Hlo, HLD, Wp1h, Wp1l,
                                                       nullptr, dinv, nullptr, tabh, nullptr, nullptr, 0);
    gather_bn_relu<<<GRID_64, 256, 0, stream>>>((const __half2*)tabh, rowptr, esrc16, dinv,
                                                b1, g1, beta1, rm1, rv1, Hhi, Hlo, 64);

    // ---- layer 2: tab = fp16(dinv*(H[:,0:128] @ W2)) ; gather -> H[:,128:192] ----
    mfma_gemm<128, 4, 0><<<GRID_MFMA, 256, 0, stream>>>(Hhi, Hlo, HLD, Wp2h, Wp2l,
                                                        nullptr, dinv, nullptr, tabh, nullptr, nullptr, 0);
    gather_bn_relu<<<GRID_64, 256, 0, stream>>>((const __half2*)tabh, rowptr, esrc16, dinv,
                                                b2, g2, beta2, rm2, rv2, Hhi, Hlo, 128);

    // ---- encoder (K=192 pre-summed; Thi/Tlo overwrite CSR region, CSR dead) ----
    mfma_gemm<192, 8, 1><<<GRID_MFMA, 256, 0, stream>>>(Hhi, Hlo, HLD, We0h, We0l,
                                                        enc_b0, nullptr, nullptr, nullptr, Thi, Tlo, 128);
    mfma_gemm<128, 4, 2><<<GRID_MFMA, 256, 0, stream>>>(Thi, Tlo, 128, We1h, We1l,
                                                        enc_b1, nullptr, hws, nullptr, nullptr, nullptr, 64);

    // ---- pool + decode ----
    pool_kernel<<<POOL_BLOCKS, 256, 0, stream>>>(hws, batch, gfeat_part, counts_part);
    dec_kernel<<<1, 256, 0, stream>>>(gfeat_part, counts_part, dec_w0, dec_b0, dec_w1, dec_b1, (float*)d_out);
}